// Round 5
// baseline (872.757 us; speedup 1.0000x reference)
//
#include <hip/hip_runtime.h>
#include <hip/hip_bf16.h>

// FluxAttention on MI355X (gfx950). Round 5:
//  - cast_weights pass DELETED: GEMMs stage B directly from f32 weights with
//    in-register f32->bf16 cvt + ds_write (saves a full 453MB HBM pass + wall).
//  - XOR block swizzle (phys = blk ^ ((row>>1)&3)) on sA (via async source
//    permutation) and sB (via write addressing): fragment b128 reads go from
//    8-way quarter-wave conflicts to 2-way (free). Kills the 1.77e7 conflicts.
//  - Flash: fixed-max softmax, split-KV x3 (unchanged from round 4).

typedef __hip_bfloat16 bf16;
typedef __attribute__((ext_vector_type(8))) short short8;
typedef __attribute__((ext_vector_type(4))) short s16x4;
typedef __attribute__((ext_vector_type(4))) float f32x4;

#define KDIM 3072
#define S_TXT 512
#define S_IMG 2048
#define S_ALL 2560
#define NHEADS 24
#define HDIM 128
#define AELEM (S_ALL * KDIM)
#define NSPLIT 3

__device__ __forceinline__ void async_ld16(const void* g, void* l) {
  __builtin_amdgcn_global_load_lds((__attribute__((address_space(1))) void*)g,
                                   (__attribute__((address_space(3))) void*)l,
                                   16, 0, 0);
}

__device__ __forceinline__ short bf16_bits(float x) {
  bf16 h = (bf16)x;
  return __builtin_bit_cast(short, h);
}
__device__ __forceinline__ float bits_f32(short s) {
  return (float)__builtin_bit_cast(bf16, s);
}

// XE rows: [0,512) = enc (txt), [512,2560) = x (img) — concat order of the ref.
__global__ __launch_bounds__(256) void cast_acts_kernel(
    const float* __restrict__ x, const float* __restrict__ enc,
    bf16* __restrict__ xe) {
  const size_t i0 = ((size_t)blockIdx.x * 256 + threadIdx.x) * 8;
  const size_t TXT = (size_t)S_TXT * KDIM;
  const float* __restrict__ src = (i0 < TXT) ? (enc + i0) : (x + (i0 - TXT));
  const float4 f0 = *(const float4*)(src);
  const float4 f1 = *(const float4*)(src + 4);
  short8 o;
  o[0] = bf16_bits(f0.x); o[1] = bf16_bits(f0.y);
  o[2] = bf16_bits(f0.z); o[3] = bf16_bits(f0.w);
  o[4] = bf16_bits(f1.x); o[5] = bf16_bits(f1.y);
  o[6] = bf16_bits(f1.z); o[7] = bf16_bits(f1.w);
  *(short8*)(xe + i0) = o;
}

// ---------------------------------------------------------------------------
// 128x128 NT GEMM tile core: C = A(bf16) * B(f32 weights)^T + bias, K = KDIM.
// A staged via global_load_lds (XOR-swizzled by source permutation).
// B staged f32->bf16 in-register (4x dwordx4 + cvt + 2x swizzled ds_write_b128).
// TRANS=true: bf16 C written transposed as C[col*S_ALL + row] (VT layout).
// ---------------------------------------------------------------------------
template <typename OutT, bool TRANS>
__device__ __forceinline__ void gemm_tile(const bf16* __restrict__ A,
                                          const float* __restrict__ B,
                                          OutT* __restrict__ C,
                                          const float* __restrict__ bias) {
  __shared__ alignas(16) short sA[128 * 32];
  __shared__ alignas(16) short sB[128 * 32];
  const int tid = threadIdx.x;
  const int lane = tid & 63;
  const int w = tid >> 6;
  const int a = lane & 15;
  const int g = lane >> 4;
  const int wm = (w >> 1) * 64;
  const int wn = (w & 1) * 64;

  f32x4 acc[4][4] = {};

  // A async staging: slot s holds phys block (s&3) of row (s>>2); source the
  // LOGICAL block (s&3)^((row>>1)&3) so reads can un-swizzle.
  const int s0 = tid, s1 = tid + 256;
  const int r0 = s0 >> 2, b0 = (s0 & 3) ^ ((r0 >> 1) & 3);
  const int r1 = s1 >> 2, b1 = (s1 & 3) ^ ((r1 >> 1) & 3);
  const bf16* gA0 = A + (size_t)r0 * KDIM + b0 * 8;
  const bf16* gA1 = A + (size_t)r1 * KDIM + b1 * 8;
  short* lA0 = sA + (w * 64) * 8;    // + lane*16B implicit in HW
  short* lA1 = sA + (256 + w * 64) * 8;

  // B staging: thread covers row = tid>>1, f32 k in [bh*16, bh*16+16).
  const int brow = tid >> 1, bh = tid & 1;
  const float* gB = B + (size_t)brow * KDIM + bh * 16;
  const int bsw = (brow >> 1) & 3;
  short* lB0 = sB + brow * 32 + (((bh * 2 + 0) ^ bsw) * 8);
  short* lB1 = sB + brow * 32 + (((bh * 2 + 1) ^ bsw) * 8);

  for (int k0 = 0; k0 < KDIM; k0 += 32) {
    __syncthreads();   // previous iter's ds_reads done before overwrite
    async_ld16(gA0 + k0, lA0);
    async_ld16(gA1 + k0, lA1);
    const float4 f0 = *(const float4*)(gB + k0);
    const float4 f1 = *(const float4*)(gB + k0 + 4);
    const float4 f2 = *(const float4*)(gB + k0 + 8);
    const float4 f3 = *(const float4*)(gB + k0 + 12);
    short8 p0, p1;
    p0[0] = bf16_bits(f0.x); p0[1] = bf16_bits(f0.y);
    p0[2] = bf16_bits(f0.z); p0[3] = bf16_bits(f0.w);
    p0[4] = bf16_bits(f1.x); p0[5] = bf16_bits(f1.y);
    p0[6] = bf16_bits(f1.z); p0[7] = bf16_bits(f1.w);
    p1[0] = bf16_bits(f2.x); p1[1] = bf16_bits(f2.y);
    p1[2] = bf16_bits(f2.z); p1[3] = bf16_bits(f2.w);
    p1[4] = bf16_bits(f3.x); p1[5] = bf16_bits(f3.y);
    p1[6] = bf16_bits(f3.z); p1[7] = bf16_bits(f3.w);
    *(short8*)lB0 = p0;
    *(short8*)lB1 = p1;
    __syncthreads();   // drains vmcnt (A async) + lgkm (B writes)
    short8 af[4], bfg[4];
#pragma unroll
    for (int i = 0; i < 4; i++) {
      const int R = wm + i * 16 + a;
      af[i] = *(const short8*)(sA + R * 32 + ((g ^ ((R >> 1) & 3)) * 8));
    }
#pragma unroll
    for (int j = 0; j < 4; j++) {
      const int R = wn + j * 16 + a;
      bfg[j] = *(const short8*)(sB + R * 32 + ((g ^ ((R >> 1) & 3)) * 8));
    }
#pragma unroll
    for (int i = 0; i < 4; i++)
#pragma unroll
      for (int j = 0; j < 4; j++)
        acc[i][j] = __builtin_amdgcn_mfma_f32_16x16x32_bf16(af[i], bfg[j], acc[i][j], 0, 0, 0);
  }

  // C/D layout: col = lane&15, row = (lane>>4)*4 + reg (m89-verified).
  if constexpr (TRANS) {
#pragma unroll
    for (int i = 0; i < 4; i++)
#pragma unroll
      for (int j = 0; j < 4; j++) {
        const int col = wn + j * 16 + a;
        const float bv = bias ? bias[col] : 0.0f;
        s16x4 pk;
#pragma unroll
        for (int r = 0; r < 4; r++) pk[r] = bf16_bits(acc[i][j][r] + bv);
        *(s16x4*)((short*)C + (size_t)col * S_ALL + wm + i * 16 + g * 4) = pk;
      }
  } else {
#pragma unroll
    for (int i = 0; i < 4; i++)
#pragma unroll
      for (int j = 0; j < 4; j++) {
        const int col = wn + j * 16 + a;
        const float bv = bias ? bias[col] : 0.0f;
#pragma unroll
        for (int r = 0; r < 4; r++) {
          const int row = wm + i * 16 + g * 4 + r;
          C[(size_t)row * KDIM + col] = (OutT)(acc[i][j][r] + bv);
        }
      }
  }
}

// Fused QKV projection: grid (20, 72). Rows in concat order (txt 0..511 first).
// which = bn/24: 0=Q 1=K 2=V(transposed into VT). Weights are raw f32 inputs.
__global__ __launch_bounds__(256) void qkv_kernel(
    const bf16* __restrict__ XE,
    const float* __restrict__ wq, const float* __restrict__ wk, const float* __restrict__ wv,
    const float* __restrict__ waq, const float* __restrict__ wak, const float* __restrict__ wav,
    const float* __restrict__ bq, const float* __restrict__ bk, const float* __restrict__ bv,
    bf16* __restrict__ Q, bf16* __restrict__ K, bf16* __restrict__ VT) {
  const int bm = blockIdx.x;
  const int bn = blockIdx.y;
  const int which = bn / 24;
  const int nc = (bn % 24) * 128;
  const bool txt = bm < 4;
  const float* W;
  if (which == 0)      W = txt ? waq : wq;
  else if (which == 1) W = txt ? wak : wk;
  else                 W = txt ? wav : wv;
  W += (size_t)nc * KDIM;
  const float* bias = nullptr;
  if (txt) bias = ((which == 0) ? bq : (which == 1) ? bk : bv) + nc;
  const int crow = bm * 128;
  const bf16* A = XE + (size_t)crow * KDIM;
  if (which == 2) {
    gemm_tile<bf16, true>(A, W, VT + (size_t)nc * S_ALL + crow, bias);
  } else {
    bf16* Out = (which == 0) ? Q : K;
    gemm_tile<bf16, false>(A, W, Out + (size_t)crow * KDIM + nc, bias);
  }
}

// Output projection: grid (20, 24). d_out: img (2048x3072) then enc (512x3072), f32.
__global__ __launch_bounds__(256) void outproj_kernel(
    const bf16* __restrict__ Obuf,
    const float* __restrict__ w_out, const float* __restrict__ b_out,
    const float* __restrict__ w_add, const float* __restrict__ b_add,
    float* __restrict__ out) {
  const int bm = blockIdx.x;
  const int bn = blockIdx.y;
  const bool txt = bm < 4;
  const bf16* A = Obuf + (size_t)bm * 128 * KDIM;
  const float* W = txt ? w_add : w_out;
  const float* bias = txt ? b_add : b_out;
  float* C = txt ? (out + (size_t)S_IMG * KDIM + (size_t)bm * 128 * KDIM)
                 : (out + (size_t)(bm - 4) * 128 * KDIM);
  gemm_tile<float, false>(A, W + (size_t)bn * 128 * KDIM, C + bn * 128, bias + bn * 128);
}

// RMS-norm + RoPE in-place. Q additionally pre-scaled by (1/sqrt(128))*log2(e)
// so the QK^T MFMA in flash emits exp2-domain scores directly.
__global__ __launch_bounds__(256) void norm_rope_kernel(
    bf16* __restrict__ Q, bf16* __restrict__ K,
    const float* __restrict__ rc, const float* __restrict__ rs,
    const float* __restrict__ nqw, const float* __restrict__ nkw,
    const float* __restrict__ naqw, const float* __restrict__ nakw) {
  const int row = blockIdx.x;
  const int h = blockIdx.y * 4 + (threadIdx.x >> 6);
  const int t = threadIdx.x & 63;
  const long base = (long)row * KDIM + h * HDIM;
  const int d0 = 2 * t, d1 = d0 + 1;
  const bool txt = row < S_TXT;
  const float QSCL = 0.08838834764831845f * 1.4426950408889634f;
  float qa = (float)Q[base + d0], qb = (float)Q[base + d1];
  float ka = (float)K[base + d0], kb = (float)K[base + d1];
  float sq = qa * qa + qb * qb;
  float sk = ka * ka + kb * kb;
#pragma unroll
  for (int m = 1; m < 64; m <<= 1) {
    sq += __shfl_xor(sq, m);
    sk += __shfl_xor(sk, m);
  }
  const float rq = rsqrtf(sq * (1.0f / 128.0f) + 1e-5f) * QSCL;
  const float rk = rsqrtf(sk * (1.0f / 128.0f) + 1e-5f);
  const float* qw = txt ? naqw : nqw;
  const float* kw = txt ? nakw : nkw;
  const float c0 = rc[row * HDIM + d0], c1 = rc[row * HDIM + d1];
  const float s0 = rs[row * HDIM + d0], s1 = rs[row * HDIM + d1];
  const float qn0 = qa * rq * qw[d0], qn1 = qb * rq * qw[d1];
  const float kn0 = ka * rk * kw[d0], kn1 = kb * rk * kw[d1];
  Q[base + d0] = (bf16)(qn0 * c0 - qn1 * s0);
  Q[base + d1] = (bf16)(qn1 * c1 + qn0 * s1);
  K[base + d0] = (bf16)(kn0 * c0 - kn1 * s0);
  K[base + d1] = (bf16)(kn1 * c1 + kn0 * s1);
}

// ---------------------------------------------------------------------------
// Flash attention, split-KV x3, FIXED-MAX softmax (p = exp2(score), scores
// bounded -> f32-safe). grid (20 q-tiles, 24 heads, 3 splits), 4 waves.
// S^T = K*Q^T so P lands A-operand-friendly; no cross-lane ops in KV loop.
// ---------------------------------------------------------------------------
__global__ __launch_bounds__(256) void flash_kernel(
    const bf16* __restrict__ Q, const bf16* __restrict__ Kb,
    const bf16* __restrict__ VT,
    bf16* __restrict__ Op0, bf16* __restrict__ Op1, bf16* __restrict__ Op2,
    float* __restrict__ L) {
  __shared__ alignas(16) short sK[64 * 128];
  __shared__ alignas(16) short sVT[128 * 64];
  __shared__ alignas(16) short sP[4][32 * 72];
  const int tid = threadIdx.x;
  const int lane = tid & 63;
  const int w = tid >> 6;
  const int a = lane & 15;
  const int g = lane >> 4;
  const int qt = blockIdx.x;
  const int h = blockIdx.y;
  const int split = blockIdx.z;
  const int it0 = split * 13;
  const int it1 = (split == 2) ? 40 : (it0 + 13);
  const int qrow0 = qt * 128 + w * 32;
  short* const sPw = sP[w];

  short8 qf[2][4];
#pragma unroll
  for (int mi = 0; mi < 2; mi++)
#pragma unroll
    for (int kk = 0; kk < 4; kk++)
      qf[mi][kk] = *(const short8*)(Q + (size_t)(qrow0 + mi * 16 + a) * KDIM + h * HDIM + kk * 32 + g * 8);

  f32x4 oacc[2][8] = {};
  float lsum[2] = {0.0f, 0.0f};

  for (int it = it0; it < it1; ++it) {
    const int kv0 = it * 64;
    __syncthreads();
#pragma unroll
    for (int is = 0; is < 4; is++) {
      const int s = is * 256 + w * 64 + lane;
      const int kr = s >> 4, p = s & 15;
      const int lb = (p - (kr & 7)) & 15;
      async_ld16(Kb + (size_t)(kv0 + kr) * KDIM + h * HDIM + lb * 8,
                 sK + (is * 256 + w * 64) * 8);
    }
#pragma unroll
    for (int is = 0; is < 4; is++) {
      const int s = is * 256 + w * 64 + lane;
      const int dr = s >> 3, p = s & 7;
      const int lb = (p - (dr & 7)) & 7;
      async_ld16(VT + (size_t)(h * HDIM + dr) * S_ALL + kv0 + lb * 8,
                 sVT + (is * 256 + w * 64) * 8);
    }
    __syncthreads();

    f32x4 st[4][2] = {};
#pragma unroll
    for (int kk = 0; kk < 4; kk++) {
      short8 kf[4];
#pragma unroll
      for (int ni = 0; ni < 4; ni++) {
        const int kr = ni * 16 + a;
        const int p = ((kk * 4 + g) + (kr & 7)) & 15;
        kf[ni] = *(const short8*)(sK + kr * 128 + p * 8);
      }
#pragma unroll
      for (int ni = 0; ni < 4; ni++)
#pragma unroll
        for (int mi = 0; mi < 2; mi++)
          st[ni][mi] = __builtin_amdgcn_mfma_f32_16x16x32_bf16(kf[ni], qf[mi][kk], st[ni][mi], 0, 0, 0);
    }

#pragma unroll
    for (int mi = 0; mi < 2; mi++)
#pragma unroll
      for (int ni = 0; ni < 4; ni++) {
        s16x4 pk;
#pragma unroll
        for (int r = 0; r < 4; r++) {
          const float p = exp2f(st[ni][mi][r]);
          lsum[mi] += p;
          pk[r] = bf16_bits(p);
        }
        *(s16x4*)(sPw + (mi * 16 + a) * 72 + ni * 16 + g * 4) = pk;
      }

#pragma unroll
    for (int ks = 0; ks < 2; ks++) {
      short8 pf[2];
#pragma unroll
      for (int mi = 0; mi < 2; mi++)
        pf[mi] = *(const short8*)(sPw + (mi * 16 + a) * 72 + ks * 32 + g * 8);
#pragma unroll
      for (int nd = 0; nd < 8; nd++) {
        const int dr = nd * 16 + a;
        const int p = ((ks * 4 + g) + (dr & 7)) & 7;
        const short8 vf = *(const short8*)(sVT + dr * 64 + p * 8);
#pragma unroll
        for (int mi = 0; mi < 2; mi++)
          oacc[mi][nd] = __builtin_amdgcn_mfma_f32_16x16x32_bf16(pf[mi], vf, oacc[mi][nd], 0, 0, 0);
      }
    }
  }

#pragma unroll
  for (int mi = 0; mi < 2; mi++) {
    lsum[mi] += __shfl_xor(lsum[mi], 16);
    lsum[mi] += __shfl_xor(lsum[mi], 32);
  }
  bf16* __restrict__ Op = (split == 0) ? Op0 : (split == 1) ? Op1 : Op2;
#pragma unroll
  for (int mi = 0; mi < 2; mi++) {
#pragma unroll
    for (int r = 0; r < 4; r++) {
      const float inv = 1.0f / __shfl(lsum[mi], g * 4 + r);
      const size_t row = qrow0 + mi * 16 + g * 4 + r;
#pragma unroll
      for (int nd = 0; nd < 8; nd++)
        Op[row * KDIM + h * HDIM + nd * 16 + a] = (bf16)(oacc[mi][nd][r] * inv);
    }
    if (g == 0)
      L[((size_t)split * NHEADS + h) * S_ALL + qrow0 + mi * 16 + a] = lsum[mi];
  }
}

// Merge 3 KV-split partials: O = sum(l_i * O_i) / sum(l_i). In-place into O0.
__global__ __launch_bounds__(256) void merge_kernel(
    bf16* __restrict__ O0, const bf16* __restrict__ O1, const bf16* __restrict__ O2,
    const float* __restrict__ L) {
  const size_t i0 = ((size_t)blockIdx.x * 256 + threadIdx.x) * 8;
  const int row = (int)(i0 / KDIM);
  const int h = (int)((i0 % KDIM) >> 7);
  const float l0 = L[((size_t)0 * NHEADS + h) * S_ALL + row];
  const float l1 = L[((size_t)1 * NHEADS + h) * S_ALL + row];
  const float l2 = L[((size_t)2 * NHEADS + h) * S_ALL + row];
  const float inv = 1.0f / (l0 + l1 + l2);
  const float w0 = l0 * inv, w1 = l1 * inv, w2 = l2 * inv;
  const short8 v0 = *(const short8*)(O0 + i0);
  const short8 v1 = *(const short8*)(O1 + i0);
  const short8 v2 = *(const short8*)(O2 + i0);
  short8 o;
#pragma unroll
  for (int u = 0; u < 8; u++)
    o[u] = bf16_bits(w0 * bits_f32(v0[u]) + w1 * bits_f32(v1[u]) + w2 * bits_f32(v2[u]));
  *(short8*)(O0 + i0) = o;
}

extern "C" void kernel_launch(void* const* d_in, const int* in_sizes, int n_in,
                              void* d_out, int out_size, void* d_ws, size_t ws_size,
                              hipStream_t stream) {
  const float* x    = (const float*)d_in[0];
  const float* enc  = (const float*)d_in[1];
  const float* rc   = (const float*)d_in[2];
  const float* rs   = (const float*)d_in[3];
  const float* wq   = (const float*)d_in[4];
  const float* wk   = (const float*)d_in[5];
  const float* wv   = (const float*)d_in[6];
  const float* waq  = (const float*)d_in[7];
  const float* wak  = (const float*)d_in[8];
  const float* wav  = (const float*)d_in[9];
  const float* bq   = (const float*)d_in[10];
  const float* bk   = (const float*)d_in[11];
  const float* bv   = (const float*)d_in[12];
  const float* nqw  = (const float*)d_in[13];
  const float* nkw  = (const float*)d_in[14];
  const float* naqw = (const float*)d_in[15];
  const float* nakw = (const float*)d_in[16];
  const float* w_out     = (const float*)d_in[17];
  const float* b_out     = (const float*)d_in[18];
  const float* w_add_out = (const float*)d_in[19];
  const float* b_add_out = (const float*)d_in[20];

  // ws layout (bf16): XE(->Opart2) | Q | K | VT | Obuf(=Opart0) | Op1 | L(f32)
  bf16* XE   = (bf16*)d_ws;
  bf16* Q    = XE + AELEM;
  bf16* K    = Q + AELEM;
  bf16* VT   = K + AELEM;
  bf16* Obuf = VT + AELEM;           // Opart split 0
  bf16* Op1  = Obuf + AELEM;         // Opart split 1
  bf16* Op2  = XE;                   // reuse XE (dead after qkv)
  float* L   = (float*)(Op1 + AELEM);

  cast_acts_kernel<<<dim3(AELEM / 2048), 256, 0, stream>>>(x, enc, XE);
  qkv_kernel<<<dim3(20, 72), 256, 0, stream>>>(XE, wq, wk, wv, waq, wak, wav,
                                               bq, bk, bv, Q, K, VT);
  norm_rope_kernel<<<dim3(S_ALL, 6), 256, 0, stream>>>(Q, K, rc, rs, nqw, nkw, naqw, nakw);
  flash_kernel<<<dim3(20, NHEADS, NSPLIT), 256, 0, stream>>>(Q, K, VT, Obuf, Op1, Op2, L);
  merge_kernel<<<dim3(AELEM / 2048), 256, 0, stream>>>(Obuf, Op1, Op2, L);
  outproj_kernel<<<dim3(20, NHEADS), 256, 0, stream>>>(Obuf, w_out, b_out,
                                                       w_add_out, b_add_out, (float*)d_out);
}

// Round 6
// 757.147 us; speedup vs baseline: 1.1527x; 1.1527x over previous
//
#include <hip/hip_runtime.h>
#include <hip/hip_bf16.h>

// FluxAttention on MI355X (gfx950). Round 6 = round 4 + XOR swizzle, minus the
// round-5 fused-cast regression:
//  - cast_weights pass restored (B staged async as bf16 — keeps load latency
//    in the vmcnt queue; round 5 proved sync VGPR staging is latency-bound).
//  - XOR block swizzle on BOTH GEMM LDS tiles via per-lane SOURCE permutation
//    of global_load_lds (dest stays lane-linear); fragment reads un-swizzle
//    with phys = g ^ ((row>>1)&3). Round 5 measured 0 conflicts for this.
//  - Flash: fixed-max softmax, split-KV x3, S^T=K*Q^T, VT global (round 4).

typedef __hip_bfloat16 bf16;
typedef __attribute__((ext_vector_type(8))) short short8;
typedef __attribute__((ext_vector_type(4))) short s16x4;
typedef __attribute__((ext_vector_type(4))) float f32x4;

#define KDIM 3072
#define S_TXT 512
#define S_IMG 2048
#define S_ALL 2560
#define NHEADS 24
#define HDIM 128
#define WELEM (KDIM * KDIM)
#define AELEM (S_ALL * KDIM)
#define NSPLIT 3

__device__ __forceinline__ void async_ld16(const void* g, void* l) {
  __builtin_amdgcn_global_load_lds((__attribute__((address_space(1))) void*)g,
                                   (__attribute__((address_space(3))) void*)l,
                                   16, 0, 0);
}

__device__ __forceinline__ short bf16_bits(float x) {
  bf16 h = (bf16)x;
  return __builtin_bit_cast(short, h);
}
__device__ __forceinline__ float bits_f32(short s) {
  return (float)__builtin_bit_cast(bf16, s);
}

// ---------------------------------------------------------------------------
// Cast kernels: f32 -> bf16, 8 elems/thread, 16B stores.
// ---------------------------------------------------------------------------
__global__ __launch_bounds__(256) void cast_weights_kernel(
    const float* __restrict__ w0, const float* __restrict__ w1,
    const float* __restrict__ w2, const float* __restrict__ w3,
    const float* __restrict__ w4, const float* __restrict__ w5,
    const float* __restrict__ w6, const float* __restrict__ w7,
    bf16* __restrict__ dst) {
  const float* srcs[8] = {w0, w1, w2, w3, w4, w5, w6, w7};
  const float* __restrict__ src = srcs[blockIdx.y];
  bf16* __restrict__ out = dst + (size_t)blockIdx.y * WELEM;
  const size_t i0 = ((size_t)blockIdx.x * 256 + threadIdx.x) * 8;
  const float4 f0 = *(const float4*)(src + i0);
  const float4 f1 = *(const float4*)(src + i0 + 4);
  short8 o;
  o[0] = bf16_bits(f0.x); o[1] = bf16_bits(f0.y);
  o[2] = bf16_bits(f0.z); o[3] = bf16_bits(f0.w);
  o[4] = bf16_bits(f1.x); o[5] = bf16_bits(f1.y);
  o[6] = bf16_bits(f1.z); o[7] = bf16_bits(f1.w);
  *(short8*)(out + i0) = o;
}

// XE rows: [0,512) = enc (txt), [512,2560) = x (img) — concat order of the ref.
__global__ __launch_bounds__(256) void cast_acts_kernel(
    const float* __restrict__ x, const float* __restrict__ enc,
    bf16* __restrict__ xe) {
  const size_t i0 = ((size_t)blockIdx.x * 256 + threadIdx.x) * 8;
  const size_t TXT = (size_t)S_TXT * KDIM;
  const float* __restrict__ src = (i0 < TXT) ? (enc + i0) : (x + (i0 - TXT));
  const float4 f0 = *(const float4*)(src);
  const float4 f1 = *(const float4*)(src + 4);
  short8 o;
  o[0] = bf16_bits(f0.x); o[1] = bf16_bits(f0.y);
  o[2] = bf16_bits(f0.z); o[3] = bf16_bits(f0.w);
  o[4] = bf16_bits(f1.x); o[5] = bf16_bits(f1.y);
  o[6] = bf16_bits(f1.z); o[7] = bf16_bits(f1.w);
  *(short8*)(xe + i0) = o;
}

// ---------------------------------------------------------------------------
// 128x128 NT GEMM tile core (C = A * B^T + bias), K = KDIM, A/B bf16.
// Both tiles staged via global_load_lds with XOR source-permute swizzle:
// slot s (row = s>>2, phys block p = s&3) sources logical block
// p ^ ((row>>1)&3); fragment reads use phys = g ^ ((row>>1)&3) -> 2-way
// bank access (free). TRANS=true: bf16 C transposed as C[col*S_ALL+row].
// ---------------------------------------------------------------------------
template <typename OutT, bool TRANS>
__device__ __forceinline__ void gemm_tile(const bf16* __restrict__ A,
                                          const bf16* __restrict__ B,
                                          OutT* __restrict__ C,
                                          const float* __restrict__ bias) {
  __shared__ alignas(16) short sA[128 * 32];
  __shared__ alignas(16) short sB[128 * 32];
  const int tid = threadIdx.x;
  const int lane = tid & 63;
  const int w = tid >> 6;
  const int a = lane & 15;
  const int g = lane >> 4;
  const int wm = (w >> 1) * 64;
  const int wn = (w & 1) * 64;

  f32x4 acc[4][4] = {};

  const int s0 = tid, s1 = tid + 256;
  const int r0 = s0 >> 2, b0 = (s0 & 3) ^ ((r0 >> 1) & 3);
  const int r1 = s1 >> 2, b1 = (s1 & 3) ^ ((r1 >> 1) & 3);
  const bf16* gA0 = A + (size_t)r0 * KDIM + b0 * 8;
  const bf16* gA1 = A + (size_t)r1 * KDIM + b1 * 8;
  const bf16* gB0 = B + (size_t)r0 * KDIM + b0 * 8;
  const bf16* gB1 = B + (size_t)r1 * KDIM + b1 * 8;
  short* lA0 = sA + (w * 64) * 8;    // + lane*16B implicit in HW
  short* lA1 = sA + (256 + w * 64) * 8;
  short* lB0 = sB + (w * 64) * 8;
  short* lB1 = sB + (256 + w * 64) * 8;

  for (int k0 = 0; k0 < KDIM; k0 += 32) {
    __syncthreads();   // previous iter's ds_reads done before overwrite
    async_ld16(gA0 + k0, lA0);
    async_ld16(gA1 + k0, lA1);
    async_ld16(gB0 + k0, lB0);
    async_ld16(gB1 + k0, lB1);
    __syncthreads();   // drains vmcnt(0) before s_barrier
    short8 af[4], bfg[4];
#pragma unroll
    for (int i = 0; i < 4; i++) {
      const int R = wm + i * 16 + a;
      af[i] = *(const short8*)(sA + R * 32 + ((g ^ ((R >> 1) & 3)) * 8));
    }
#pragma unroll
    for (int j = 0; j < 4; j++) {
      const int R = wn + j * 16 + a;
      bfg[j] = *(const short8*)(sB + R * 32 + ((g ^ ((R >> 1) & 3)) * 8));
    }
#pragma unroll
    for (int i = 0; i < 4; i++)
#pragma unroll
      for (int j = 0; j < 4; j++)
        acc[i][j] = __builtin_amdgcn_mfma_f32_16x16x32_bf16(af[i], bfg[j], acc[i][j], 0, 0, 0);
  }

  // C/D layout: col = lane&15, row = (lane>>4)*4 + reg (m89-verified).
  if constexpr (TRANS) {
#pragma unroll
    for (int i = 0; i < 4; i++)
#pragma unroll
      for (int j = 0; j < 4; j++) {
        const int col = wn + j * 16 + a;
        const float bv = bias ? bias[col] : 0.0f;
        s16x4 pk;
#pragma unroll
        for (int r = 0; r < 4; r++) pk[r] = bf16_bits(acc[i][j][r] + bv);
        *(s16x4*)((short*)C + (size_t)col * S_ALL + wm + i * 16 + g * 4) = pk;
      }
  } else {
#pragma unroll
    for (int i = 0; i < 4; i++)
#pragma unroll
      for (int j = 0; j < 4; j++) {
        const int col = wn + j * 16 + a;
        const float bv = bias ? bias[col] : 0.0f;
#pragma unroll
        for (int r = 0; r < 4; r++) {
          const int row = wm + i * 16 + g * 4 + r;
          C[(size_t)row * KDIM + col] = (OutT)(acc[i][j][r] + bv);
        }
      }
  }
}

// Fused QKV projection: grid (20, 72). Rows in concat order (txt 0..511 first).
__global__ __launch_bounds__(256) void qkv_kernel(
    const bf16* __restrict__ XE, const bf16* __restrict__ Wc,
    const float* __restrict__ bq, const float* __restrict__ bk, const float* __restrict__ bv,
    bf16* __restrict__ Q, bf16* __restrict__ K, bf16* __restrict__ VT) {
  const int bm = blockIdx.x;
  const int bn = blockIdx.y;
  const int which = bn / 24;
  const int nc = (bn % 24) * 128;
  const bool txt = bm < 4;
  const bf16* W = Wc + (size_t)(txt ? (3 + which) : which) * WELEM + (size_t)nc * KDIM;
  const float* bias = nullptr;
  if (txt) bias = ((which == 0) ? bq : (which == 1) ? bk : bv) + nc;
  const int crow = bm * 128;
  const bf16* A = XE + (size_t)crow * KDIM;
  if (which == 2) {
    gemm_tile<bf16, true>(A, W, VT + (size_t)nc * S_ALL + crow, bias);
  } else {
    bf16* Out = (which == 0) ? Q : K;
    gemm_tile<bf16, false>(A, W, Out + (size_t)crow * KDIM + nc, bias);
  }
}

// Output projection: grid (20, 24). d_out: img (2048x3072) then enc (512x3072), f32.
__global__ __launch_bounds__(256) void outproj_kernel(
    const bf16* __restrict__ Obuf, const bf16* __restrict__ Wc,
    const float* __restrict__ b_out, const float* __restrict__ b_add,
    float* __restrict__ out) {
  const int bm = blockIdx.x;
  const int bn = blockIdx.y;
  const bool txt = bm < 4;
  const bf16* A = Obuf + (size_t)bm * 128 * KDIM;
  const bf16* W = Wc + (size_t)(txt ? 7 : 6) * WELEM;
  const float* bias = txt ? b_add : b_out;
  float* C = txt ? (out + (size_t)S_IMG * KDIM + (size_t)bm * 128 * KDIM)
                 : (out + (size_t)(bm - 4) * 128 * KDIM);
  gemm_tile<float, false>(A, W + (size_t)bn * 128 * KDIM, C + bn * 128, bias + bn * 128);
}

// RMS-norm + RoPE in-place. Q additionally pre-scaled by (1/sqrt(128))*log2(e)
// so the QK^T MFMA in flash emits exp2-domain scores directly.
__global__ __launch_bounds__(256) void norm_rope_kernel(
    bf16* __restrict__ Q, bf16* __restrict__ K,
    const float* __restrict__ rc, const float* __restrict__ rs,
    const float* __restrict__ nqw, const float* __restrict__ nkw,
    const float* __restrict__ naqw, const float* __restrict__ nakw) {
  const int row = blockIdx.x;
  const int h = blockIdx.y * 4 + (threadIdx.x >> 6);
  const int t = threadIdx.x & 63;
  const long base = (long)row * KDIM + h * HDIM;
  const int d0 = 2 * t, d1 = d0 + 1;
  const bool txt = row < S_TXT;
  const float QSCL = 0.08838834764831845f * 1.4426950408889634f;
  float qa = (float)Q[base + d0], qb = (float)Q[base + d1];
  float ka = (float)K[base + d0], kb = (float)K[base + d1];
  float sq = qa * qa + qb * qb;
  float sk = ka * ka + kb * kb;
#pragma unroll
  for (int m = 1; m < 64; m <<= 1) {
    sq += __shfl_xor(sq, m);
    sk += __shfl_xor(sk, m);
  }
  const float rq = rsqrtf(sq * (1.0f / 128.0f) + 1e-5f) * QSCL;
  const float rk = rsqrtf(sk * (1.0f / 128.0f) + 1e-5f);
  const float* qw = txt ? naqw : nqw;
  const float* kw = txt ? nakw : nkw;
  const float c0 = rc[row * HDIM + d0], c1 = rc[row * HDIM + d1];
  const float s0 = rs[row * HDIM + d0], s1 = rs[row * HDIM + d1];
  const float qn0 = qa * rq * qw[d0], qn1 = qb * rq * qw[d1];
  const float kn0 = ka * rk * kw[d0], kn1 = kb * rk * kw[d1];
  Q[base + d0] = (bf16)(qn0 * c0 - qn1 * s0);
  Q[base + d1] = (bf16)(qn1 * c1 + qn0 * s1);
  K[base + d0] = (bf16)(kn0 * c0 - kn1 * s0);
  K[base + d1] = (bf16)(kn1 * c1 + kn0 * s1);
}

// ---------------------------------------------------------------------------
// Flash attention, split-KV x3, FIXED-MAX softmax (p = exp2(score), scores
// bounded -> f32-safe). grid (20 q-tiles, 24 heads, 3 splits), 4 waves.
// S^T = K*Q^T so P lands A-operand-friendly; no cross-lane ops in KV loop.
// ---------------------------------------------------------------------------
__global__ __launch_bounds__(256) void flash_kernel(
    const bf16* __restrict__ Q, const bf16* __restrict__ Kb,
    const bf16* __restrict__ VT,
    bf16* __restrict__ Op0, bf16* __restrict__ Op1, bf16* __restrict__ Op2,
    float* __restrict__ L) {
  __shared__ alignas(16) short sK[64 * 128];
  __shared__ alignas(16) short sVT[128 * 64];
  __shared__ alignas(16) short sP[4][32 * 72];
  const int tid = threadIdx.x;
  const int lane = tid & 63;
  const int w = tid >> 6;
  const int a = lane & 15;
  const int g = lane >> 4;
  const int qt = blockIdx.x;
  const int h = blockIdx.y;
  const int split = blockIdx.z;
  const int it0 = split * 13;
  const int it1 = (split == 2) ? 40 : (it0 + 13);
  const int qrow0 = qt * 128 + w * 32;
  short* const sPw = sP[w];

  short8 qf[2][4];
#pragma unroll
  for (int mi = 0; mi < 2; mi++)
#pragma unroll
    for (int kk = 0; kk < 4; kk++)
      qf[mi][kk] = *(const short8*)(Q + (size_t)(qrow0 + mi * 16 + a) * KDIM + h * HDIM + kk * 32 + g * 8);

  f32x4 oacc[2][8] = {};
  float lsum[2] = {0.0f, 0.0f};

  for (int it = it0; it < it1; ++it) {
    const int kv0 = it * 64;
    __syncthreads();
#pragma unroll
    for (int is = 0; is < 4; is++) {
      const int s = is * 256 + w * 64 + lane;
      const int kr = s >> 4, p = s & 15;
      const int lb = (p - (kr & 7)) & 15;
      async_ld16(Kb + (size_t)(kv0 + kr) * KDIM + h * HDIM + lb * 8,
                 sK + (is * 256 + w * 64) * 8);
    }
#pragma unroll
    for (int is = 0; is < 4; is++) {
      const int s = is * 256 + w * 64 + lane;
      const int dr = s >> 3, p = s & 7;
      const int lb = (p - (dr & 7)) & 7;
      async_ld16(VT + (size_t)(h * HDIM + dr) * S_ALL + kv0 + lb * 8,
                 sVT + (is * 256 + w * 64) * 8);
    }
    __syncthreads();

    f32x4 st[4][2] = {};
#pragma unroll
    for (int kk = 0; kk < 4; kk++) {
      short8 kf[4];
#pragma unroll
      for (int ni = 0; ni < 4; ni++) {
        const int kr = ni * 16 + a;
        const int p = ((kk * 4 + g) + (kr & 7)) & 15;
        kf[ni] = *(const short8*)(sK + kr * 128 + p * 8);
      }
#pragma unroll
      for (int ni = 0; ni < 4; ni++)
#pragma unroll
        for (int mi = 0; mi < 2; mi++)
          st[ni][mi] = __builtin_amdgcn_mfma_f32_16x16x32_bf16(kf[ni], qf[mi][kk], st[ni][mi], 0, 0, 0);
    }

#pragma unroll
    for (int mi = 0; mi < 2; mi++)
#pragma unroll
      for (int ni = 0; ni < 4; ni++) {
        s16x4 pk;
#pragma unroll
        for (int r = 0; r < 4; r++) {
          const float p = exp2f(st[ni][mi][r]);
          lsum[mi] += p;
          pk[r] = bf16_bits(p);
        }
        *(s16x4*)(sPw + (mi * 16 + a) * 72 + ni * 16 + g * 4) = pk;
      }

#pragma unroll
    for (int ks = 0; ks < 2; ks++) {
      short8 pf[2];
#pragma unroll
      for (int mi = 0; mi < 2; mi++)
        pf[mi] = *(const short8*)(sPw + (mi * 16 + a) * 72 + ks * 32 + g * 8);
#pragma unroll
      for (int nd = 0; nd < 8; nd++) {
        const int dr = nd * 16 + a;
        const int p = ((ks * 4 + g) + (dr & 7)) & 7;
        const short8 vf = *(const short8*)(sVT + dr * 64 + p * 8);
#pragma unroll
        for (int mi = 0; mi < 2; mi++)
          oacc[mi][nd] = __builtin_amdgcn_mfma_f32_16x16x32_bf16(pf[mi], vf, oacc[mi][nd], 0, 0, 0);
      }
    }
  }

#pragma unroll
  for (int mi = 0; mi < 2; mi++) {
    lsum[mi] += __shfl_xor(lsum[mi], 16);
    lsum[mi] += __shfl_xor(lsum[mi], 32);
  }
  bf16* __restrict__ Op = (split == 0) ? Op0 : (split == 1) ? Op1 : Op2;
#pragma unroll
  for (int mi = 0; mi < 2; mi++) {
#pragma unroll
    for (int r = 0; r < 4; r++) {
      const float inv = 1.0f / __shfl(lsum[mi], g * 4 + r);
      const size_t row = qrow0 + mi * 16 + g * 4 + r;
#pragma unroll
      for (int nd = 0; nd < 8; nd++)
        Op[row * KDIM + h * HDIM + nd * 16 + a] = (bf16)(oacc[mi][nd][r] * inv);
    }
    if (g == 0)
      L[((size_t)split * NHEADS + h) * S_ALL + qrow0 + mi * 16 + a] = lsum[mi];
  }
}

// Merge 3 KV-split partials: O = sum(l_i * O_i) / sum(l_i). In-place into O0.
__global__ __launch_bounds__(256) void merge_kernel(
    bf16* __restrict__ O0, const bf16* __restrict__ O1, const bf16* __restrict__ O2,
    const float* __restrict__ L) {
  const size_t i0 = ((size_t)blockIdx.x * 256 + threadIdx.x) * 8;
  const int row = (int)(i0 / KDIM);
  const int h = (int)((i0 % KDIM) >> 7);
  const float l0 = L[((size_t)0 * NHEADS + h) * S_ALL + row];
  const float l1 = L[((size_t)1 * NHEADS + h) * S_ALL + row];
  const float l2 = L[((size_t)2 * NHEADS + h) * S_ALL + row];
  const float inv = 1.0f / (l0 + l1 + l2);
  const float w0 = l0 * inv, w1 = l1 * inv, w2 = l2 * inv;
  const short8 v0 = *(const short8*)(O0 + i0);
  const short8 v1 = *(const short8*)(O1 + i0);
  const short8 v2 = *(const short8*)(O2 + i0);
  short8 o;
#pragma unroll
  for (int u = 0; u < 8; u++)
    o[u] = bf16_bits(w0 * bits_f32(v0[u]) + w1 * bits_f32(v1[u]) + w2 * bits_f32(v2[u]));
  *(short8*)(O0 + i0) = o;
}

extern "C" void kernel_launch(void* const* d_in, const int* in_sizes, int n_in,
                              void* d_out, int out_size, void* d_ws, size_t ws_size,
                              hipStream_t stream) {
  const float* x    = (const float*)d_in[0];
  const float* enc  = (const float*)d_in[1];
  const float* rc   = (const float*)d_in[2];
  const float* rs   = (const float*)d_in[3];
  const float* wq   = (const float*)d_in[4];
  const float* wk   = (const float*)d_in[5];
  const float* wv   = (const float*)d_in[6];
  const float* waq  = (const float*)d_in[7];
  const float* wak  = (const float*)d_in[8];
  const float* wav  = (const float*)d_in[9];
  const float* bq   = (const float*)d_in[10];
  const float* bk   = (const float*)d_in[11];
  const float* bv   = (const float*)d_in[12];
  const float* nqw  = (const float*)d_in[13];
  const float* nkw  = (const float*)d_in[14];
  const float* naqw = (const float*)d_in[15];
  const float* nakw = (const float*)d_in[16];
  const float* w_out     = (const float*)d_in[17];
  const float* b_out     = (const float*)d_in[18];
  const float* w_add_out = (const float*)d_in[19];
  const float* b_add_out = (const float*)d_in[20];

  // ws layout (bf16): Wc[8*WELEM] | XE(->Opart2) | Q | K | VT | Obuf(=Opart0)
  //                   | Opart1 | L(f32)   — ~235 MiB total.
  bf16* Wc   = (bf16*)d_ws;
  bf16* XE   = Wc + (size_t)8 * WELEM;
  bf16* Q    = XE + AELEM;
  bf16* K    = Q + AELEM;
  bf16* VT   = K + AELEM;
  bf16* Obuf = VT + AELEM;           // Opart split 0
  bf16* Op1  = Obuf + AELEM;         // Opart split 1
  bf16* Op2  = XE;                   // reuse XE (dead after qkv)
  float* L   = (float*)(Op1 + AELEM);

  cast_weights_kernel<<<dim3(WELEM / 2048, 8), 256, 0, stream>>>(
      wq, wk, wv, waq, wak, wav, w_out, w_add_out, Wc);
  cast_acts_kernel<<<dim3(AELEM / 2048), 256, 0, stream>>>(x, enc, XE);

  qkv_kernel<<<dim3(20, 72), 256, 0, stream>>>(XE, Wc, bq, bk, bv, Q, K, VT);
  norm_rope_kernel<<<dim3(S_ALL, 6), 256, 0, stream>>>(Q, K, rc, rs, nqw, nkw, naqw, nakw);
  flash_kernel<<<dim3(20, NHEADS, NSPLIT), 256, 0, stream>>>(Q, K, VT, Obuf, Op1, Op2, L);
  merge_kernel<<<dim3(AELEM / 2048), 256, 0, stream>>>(Obuf, Op1, Op2, L);
  outproj_kernel<<<dim3(20, NHEADS), 256, 0, stream>>>(Obuf, Wc, b_out, b_add_out,
                                                       (float*)d_out);
}